// Round 3
// baseline (257.408 us; speedup 1.0000x reference)
//
#include <hip/hip_runtime.h>
#include <hip/hip_bf16.h>

// B=4, L=1024, D=1024, H=16, DH=64.
// Dataset dtype is UNCERTAIN (bf16 vs fp32) -> device-side probe + dual-dtype I/O.
// ws layout (byte offsets):
//   [0,8M)     Q   (4M bf16)          [8M,16M)  K        [16M,24M) V
//   [24M,32M)  conv seq (4M bf16)
//   [32M,34M)  conv Wq   [34M,36M) Wk   [36M,38M) Wv
//   [38M+0)    conv bq(1K) bk(+2KB) bv(+4KB) pmask(+8KB,4K elems)
//   [40M,48M)  attn output staging (4M bf16)
//   [48M]      int flag (1 = inputs are fp32)
// Sentinels in d_out (decode via absmax): 100=bad sizes, 200=ws too small,
//   500=NaN in attn acc, 300=inf in attn acc.

#define LL 1024

typedef __attribute__((ext_vector_type(8))) short short8;
typedef __attribute__((ext_vector_type(4))) float floatx4;

__device__ __forceinline__ float bf2f(unsigned short u) {
    return __uint_as_float(((unsigned int)u) << 16);
}
__device__ __forceinline__ unsigned short f2bf(float f) {
    unsigned int x = __float_as_uint(f);
    unsigned int r = x + 0x7fffu + ((x >> 16) & 1u);
    return (unsigned short)(r >> 16);
}
__device__ __forceinline__ unsigned short scrub1(unsigned short u) {
    return ((u & 0x7f80u) == 0x7f80u) ? (unsigned short)0 : u;  // zero NaN/Inf bf16
}

// ---- probe: detect fp32 inputs (mantissa halves contain NaN-exponent patterns) ----
__global__ void probe_dtype(const unsigned short* __restrict__ seq, int* __restrict__ flag) {
    __shared__ int cnt;
    if (threadIdx.x == 0) cnt = 0;
    __syncthreads();
    int c = 0;
    for (int i = 0; i < 128; ++i) {
        unsigned short u = seq[threadIdx.x * 128 + i];  // first 32768 ushorts
        c += ((u & 0x7f80u) == 0x7f80u) ? 1 : 0;
    }
    atomicAdd(&cnt, c);
    __syncthreads();
    if (threadIdx.x == 0) *flag = (cnt >= 8) ? 1 : 0;
}

// ---- normalize all inputs to clean bf16 in ws ----
// element map: [0,4M)=seq [4M,5M)=Wq [5M,6M)=Wk [6M,7M)=Wv
//              [7M,+1K)=bq [+1K,+2K)=bk [+2K,+3K)=bv [+3K,+7K)=pmask
__global__ __launch_bounds__(256) void conv_in(
    const int* __restrict__ flag,
    const void* __restrict__ seq, const void* __restrict__ wq,
    const void* __restrict__ wk,  const void* __restrict__ wv,
    const void* __restrict__ bq,  const void* __restrict__ bk,
    const void* __restrict__ bv,  const void* __restrict__ pm,
    unsigned short* __restrict__ ws)
{
    const int f = *flag;
    unsigned int t = blockIdx.x * 256u + threadIdx.x;   // grid 28700 -> 7,347,200
    const void* src; unsigned int idx; unsigned short* dst;
    if (t < 4194304u)      { src = seq; idx = t;            dst = ws + 12582912u; }
    else if (t < 5242880u) { src = wq;  idx = t - 4194304u; dst = ws + 16777216u; }
    else if (t < 6291456u) { src = wk;  idx = t - 5242880u; dst = ws + 17825792u; }
    else if (t < 7340032u) { src = wv;  idx = t - 6291456u; dst = ws + 18874368u; }
    else if (t < 7341056u) { src = bq;  idx = t - 7340032u; dst = ws + 19922944u; }
    else if (t < 7342080u) { src = bk;  idx = t - 7341056u; dst = ws + 19923968u; }
    else if (t < 7343104u) { src = bv;  idx = t - 7342080u; dst = ws + 19924992u; }
    else                   { src = pm;  idx = t - 7343104u; dst = ws + 19927040u; }
    unsigned short v;
    if (f) v = f2bf(((const float*)src)[idx]);
    else   v = scrub1(((const unsigned short*)src)[idx]);
    dst[idx] = v;
}

// ---------------- QKV projection (m93-pattern, verified) ----------------
__global__ __launch_bounds__(256) void qkv_proj(
    const unsigned short* __restrict__ X,
    const unsigned short* __restrict__ Wq, const unsigned short* __restrict__ bq,
    const unsigned short* __restrict__ Wk, const unsigned short* __restrict__ bk,
    const unsigned short* __restrict__ Wv, const unsigned short* __restrict__ bv,
    unsigned short* __restrict__ dst_base)
{
    const int z = blockIdx.z;
    const unsigned short* W    = (z == 0) ? Wq : ((z == 1) ? Wk : Wv);
    const unsigned short* bias = (z == 0) ? bq : ((z == 1) ? bk : bv);
    unsigned short* dst = dst_base + (size_t)z * (4096u * 1024u);

    __shared__ __align__(16) unsigned short As[128][72];
    __shared__ __align__(16) unsigned short Bs[128][72];

    const int tid  = threadIdx.x;
    const int lane = tid & 63;
    const int wave = tid >> 6;
    const int quad = lane >> 4, r16 = lane & 15;
    const int wr = wave >> 1, wc = wave & 1;
    const int m0 = blockIdx.x * 128;
    const int n0 = blockIdx.y * 128;

    floatx4 acc[4][4];
#pragma unroll
    for (int i = 0; i < 4; ++i)
#pragma unroll
        for (int j = 0; j < 4; ++j)
#pragma unroll
            for (int r = 0; r < 4; ++r) acc[i][j][r] = 0.f;

    for (int k0 = 0; k0 < 1024; k0 += 64) {
        __syncthreads();
#pragma unroll
        for (int v = 0; v < 4; ++v) {
            int vi  = tid + v * 256;
            int row = vi >> 3, cv = (vi & 7) << 3;
            *(uint4*)&As[row][cv] = *(const uint4*)(X + (size_t)(m0 + row) * 1024 + k0 + cv);
            *(uint4*)&Bs[row][cv] = *(const uint4*)(W + (size_t)(n0 + row) * 1024 + k0 + cv);
        }
        __syncthreads();

#pragma unroll
        for (int kk = 0; kk < 2; ++kk) {
            short8 a[4], b[4];
#pragma unroll
            for (int i = 0; i < 4; ++i)
                a[i] = *(const short8*)&As[wr * 64 + i * 16 + r16][kk * 32 + quad * 8];
#pragma unroll
            for (int j = 0; j < 4; ++j)
                b[j] = *(const short8*)&Bs[wc * 64 + j * 16 + r16][kk * 32 + quad * 8];
#pragma unroll
            for (int i = 0; i < 4; ++i)
#pragma unroll
                for (int j = 0; j < 4; ++j)
                    acc[i][j] = __builtin_amdgcn_mfma_f32_16x16x32_bf16(a[i], b[j], acc[i][j], 0, 0, 0);
        }
    }

#pragma unroll
    for (int j = 0; j < 4; ++j) {
        int n = n0 + wc * 64 + j * 16 + r16;
        float bvf = bf2f(bias[n]);
        int h = n >> 6, d = n & 63;
#pragma unroll
        for (int i = 0; i < 4; ++i) {
#pragma unroll
            for (int r = 0; r < 4; ++r) {
                int m = m0 + wr * 64 + i * 16 + quad * 4 + r;
                int b = m >> 10, l = m & 1023;
                dst[(((size_t)(b * 16 + h)) * 1024 + l) * 64 + d] = f2bf(acc[i][j][r] + bvf);
            }
        }
    }
}

// ---------------- Flash attention (m120-pattern) ----------------
__global__ __launch_bounds__(256) void attn(
    const unsigned short* __restrict__ Qw,
    const unsigned short* __restrict__ Kw,
    const unsigned short* __restrict__ Vw,
    const unsigned short* __restrict__ pmask,   // (B, L), clean bf16
    unsigned short* __restrict__ aout)          // (B, L, D) staging in ws
{
    __shared__ __align__(16) unsigned short Ks[128][72];
    __shared__ __align__(16) unsigned short Vt[64][136];
    __shared__ __align__(16) unsigned short Ps[4][16][136];

    const int tid  = threadIdx.x;
    const int lane = tid & 63;
    const int wave = tid >> 6;
    const int quad = lane >> 4, r16 = lane & 15;
    const int qi = blockIdx.x;
    const int bh = blockIdx.y;
    const int b  = bh >> 4, h = bh & 15;
    const int q0 = qi * 64;

    const size_t base = (size_t)bh * (1024 * 64);
    const unsigned short* Qg = Qw + base;
    const unsigned short* Kg = Kw + base;
    const unsigned short* Vg = Vw + base;

    const int qrow_frag = q0 + wave * 16 + r16;
    short8 aq0 = *(const short8*)(Qg + (size_t)qrow_frag * 64 + quad * 8);
    short8 aq1 = *(const short8*)(Qg + (size_t)qrow_frag * 64 + 32 + quad * 8);

    const int my_q_base = q0 + wave * 16 + quad * 4;

    float m_st[4], l_st[4];
    floatx4 o[4];
#pragma unroll
    for (int r = 0; r < 4; ++r) { m_st[r] = -1.0e30f; l_st[r] = 0.f; }
#pragma unroll
    for (int j = 0; j < 4; ++j)
#pragma unroll
        for (int r = 0; r < 4; ++r) o[j][r] = 0.f;

    const int ktmax = (q0 + 63) >> 7;
    for (int kt = 0; kt <= ktmax; ++kt) {
        __syncthreads();
#pragma unroll
        for (int v = 0; v < 4; ++v) {
            int vi  = tid + v * 256;
            int row = vi >> 3, cv = (vi & 7) << 3;
            *(uint4*)&Ks[row][cv] = *(const uint4*)(Kg + (size_t)(kt * 128 + row) * 64 + cv);
            uint4 t = *(const uint4*)(Vg + (size_t)(kt * 128 + row) * 64 + cv);
            unsigned int wds[4] = {t.x, t.y, t.z, t.w};
#pragma unroll
            for (int e = 0; e < 4; ++e) {
                Vt[cv + 2 * e][row]     = (unsigned short)(wds[e] & 0xffffu);
                Vt[cv + 2 * e + 1][row] = (unsigned short)(wds[e] >> 16);
            }
        }
        __syncthreads();

        floatx4 s[8];
#pragma unroll
        for (int j = 0; j < 8; ++j)
#pragma unroll
            for (int r = 0; r < 4; ++r) s[j][r] = 0.f;
#pragma unroll
        for (int j = 0; j < 8; ++j) {
            short8 bk0 = *(const short8*)&Ks[j * 16 + r16][quad * 8];
            s[j] = __builtin_amdgcn_mfma_f32_16x16x32_bf16(aq0, bk0, s[j], 0, 0, 0);
            short8 bk1 = *(const short8*)&Ks[j * 16 + r16][32 + quad * 8];
            s[j] = __builtin_amdgcn_mfma_f32_16x16x32_bf16(aq1, bk1, s[j], 0, 0, 0);
        }

        const int key_base = kt * 128;
#pragma unroll
        for (int j = 0; j < 8; ++j) {
            int key = key_base + j * 16 + r16;
            float pm = bf2f(pmask[b * LL + key]);
#pragma unroll
            for (int r = 0; r < 4; ++r) {
                float sc = s[j][r] * 0.125f + pm;
                if (key > my_q_base + r) sc -= 1.0e9f;
                s[j][r] = sc;
            }
        }

#pragma unroll
        for (int r = 0; r < 4; ++r) {
            float mx = s[0][r];
#pragma unroll
            for (int j = 1; j < 8; ++j) mx = fmaxf(mx, s[j][r]);
            mx = fmaxf(mx, __shfl_xor(mx, 1));
            mx = fmaxf(mx, __shfl_xor(mx, 2));
            mx = fmaxf(mx, __shfl_xor(mx, 4));
            mx = fmaxf(mx, __shfl_xor(mx, 8));
            float m_new = fmaxf(m_st[r], mx);
            float alpha = __expf(m_st[r] - m_new);
            float rs = 0.f;
#pragma unroll
            for (int j = 0; j < 8; ++j) {
                float p = __expf(s[j][r] - m_new);
                s[j][r] = p;
                rs += p;
            }
            rs += __shfl_xor(rs, 1);
            rs += __shfl_xor(rs, 2);
            rs += __shfl_xor(rs, 4);
            rs += __shfl_xor(rs, 8);
            l_st[r] = l_st[r] * alpha + rs;
            m_st[r] = m_new;
#pragma unroll
            for (int j2 = 0; j2 < 4; ++j2) o[j2][r] *= alpha;
        }

#pragma unroll
        for (int j = 0; j < 8; ++j)
#pragma unroll
            for (int r = 0; r < 4; ++r)
                Ps[wave][quad * 4 + r][j * 16 + r16] = f2bf(s[j][r]);

        __syncthreads();

#pragma unroll
        for (int kk4 = 0; kk4 < 4; ++kk4) {
            short8 ap = *(const short8*)&Ps[wave][r16][kk4 * 32 + quad * 8];
#pragma unroll
            for (int j2 = 0; j2 < 4; ++j2) {
                short8 bv = *(const short8*)&Vt[j2 * 16 + r16][kk4 * 32 + quad * 8];
                o[j2] = __builtin_amdgcn_mfma_f32_16x16x32_bf16(ap, bv, o[j2], 0, 0, 0);
            }
        }
    }

#pragma unroll
    for (int j2 = 0; j2 < 4; ++j2) {
        int d = j2 * 16 + r16;
#pragma unroll
        for (int r = 0; r < 4; ++r) {
            int qrow = my_q_base + r;
            float inv_l = 1.0f / fmaxf(l_st[r], 1.0e-30f);
            float val = o[j2][r] * inv_l;
            if (val != val) val = 500.0f;                // sentinel: NaN in accumulators
            else if (fabsf(val) > 100.0f) val = 300.0f;  // sentinel: inf/huge
            aout[((size_t)(b * 1024 + qrow)) * 1024 + h * 64 + d] = f2bf(val);
        }
    }
}

// ---- final output in the flagged dtype ----
__global__ __launch_bounds__(256) void conv_out(
    const int* __restrict__ flag, const unsigned short* __restrict__ aout,
    void* __restrict__ out)
{
    unsigned int t = blockIdx.x * 256u + threadIdx.x;  // grid 16384 -> 4,194,304
    if (*flag) ((float*)out)[t] = bf2f(aout[t]);
    else       ((unsigned short*)out)[t] = aout[t];
}

// ---- sentinel fill (bf16 pattern; decodes to ~same magnitude if read as fp32) ----
__global__ __launch_bounds__(256) void fill_sentinel(unsigned short* __restrict__ out,
                                                     unsigned short v, unsigned int n)
{
    unsigned int t = blockIdx.x * 256u + threadIdx.x;
    if (t < n) out[t] = v;
}

extern "C" void kernel_launch(void* const* d_in, const int* in_sizes, int n_in,
                              void* d_out, int out_size, void* d_ws, size_t ws_size,
                              hipStream_t stream) {
    bool sizes_ok = (n_in == 9) && in_sizes[0] == 4194304 && in_sizes[1] == 4096 &&
                    in_sizes[2] == 1048576 && in_sizes[3] == 1048576 && in_sizes[4] == 1024 &&
                    in_sizes[5] == 1048576 && in_sizes[6] == 1024 && in_sizes[7] == 1048576 &&
                    in_sizes[8] == 1024 && out_size == 4194304;
    if (!sizes_ok) {
        fill_sentinel<<<16384, 256, 0, stream>>>((unsigned short*)d_out, 0x42C8 /*100*/, 4194304u);
        return;
    }
    if (ws_size < 50331664u) {  // 48 MB + flag
        fill_sentinel<<<16384, 256, 0, stream>>>((unsigned short*)d_out, 0x4348 /*200*/, 4194304u);
        return;
    }

    unsigned short* ws = (unsigned short*)d_ws;
    int* flag = (int*)((char*)d_ws + 50331648u);

    probe_dtype<<<1, 256, 0, stream>>>((const unsigned short*)d_in[0], flag);

    conv_in<<<28700, 256, 0, stream>>>(flag,
        d_in[0], d_in[3], d_in[5], d_in[7], d_in[4], d_in[6], d_in[8], d_in[1], ws);

    const unsigned short* cseq = ws + 12582912u;
    const unsigned short* cwq  = ws + 16777216u;
    const unsigned short* cwk  = ws + 17825792u;
    const unsigned short* cwv  = ws + 18874368u;
    const unsigned short* cbq  = ws + 19922944u;
    const unsigned short* cbk  = ws + 19923968u;
    const unsigned short* cbv  = ws + 19924992u;
    const unsigned short* cpm  = ws + 19927040u;
    unsigned short* aout = ws + 20971520u;

    dim3 g1(32, 8, 3);
    qkv_proj<<<g1, 256, 0, stream>>>(cseq, cwq, cbq, cwk, cbk, cwv, cbv, ws);

    dim3 g2(16, 64);
    attn<<<g2, 256, 0, stream>>>(ws, ws + 4194304u, ws + 8388608u, cpm, aout);

    conv_out<<<16384, 256, 0, stream>>>(flag, aout, d_out);
}

// Round 4
// 214.319 us; speedup vs baseline: 1.2011x; 1.2011x over previous
//
#include <hip/hip_runtime.h>
#include <hip/hip_bf16.h>

// B=4, L=1024, D=1024, H=16, DH=64. Inputs are fp32 on-device (proven R0-R3:
// barrier-variant NaN persisted, dtype-adaptive passed). Probe kept as insurance.
// ws (elem offsets, bf16): Q[0,4M) K[4M,8M) V^T[8M,12M) seq[12M,16M)
//   Wq[16M,17M) Wk[17M,18M) Wv[18M,19M) bq@19922944 bk@19923968 bv@19924992
//   pmask@19927040. flag @ byte 50331648.

#define LL 1024

typedef __attribute__((ext_vector_type(8))) short short8;
typedef __attribute__((ext_vector_type(4))) float floatx4;

__device__ __forceinline__ float bf2f(unsigned short u) {
    return __uint_as_float(((unsigned int)u) << 16);
}
__device__ __forceinline__ unsigned short f2bf(float f) {
    unsigned int x = __float_as_uint(f);
    unsigned int r = x + 0x7fffu + ((x >> 16) & 1u);
    return (unsigned short)(r >> 16);
}
__device__ __forceinline__ unsigned short scrub1(unsigned short u) {
    return ((u & 0x7f80u) == 0x7f80u) ? (unsigned short)0 : u;
}

#if __has_builtin(__builtin_amdgcn_global_load_lds)
#define HAVE_GLL 1
typedef __attribute__((address_space(1))) unsigned int as1_u32;
typedef __attribute__((address_space(3))) unsigned int as3_u32;
__device__ __forceinline__ void gll16(const void* g, void* l) {
    __builtin_amdgcn_global_load_lds((const as1_u32*)g, (as3_u32*)l, 16, 0, 0);
}
#endif

// ---- probe: detect fp32 inputs ----
__global__ void probe_dtype(const unsigned short* __restrict__ seq, int* __restrict__ flag) {
    __shared__ int cnt;
    if (threadIdx.x == 0) cnt = 0;
    __syncthreads();
    int c = 0;
    for (int i = 0; i < 128; ++i) {
        unsigned short u = seq[threadIdx.x * 128 + i];
        c += ((u & 0x7f80u) == 0x7f80u) ? 1 : 0;
    }
    atomicAdd(&cnt, c);
    __syncthreads();
    if (threadIdx.x == 0) *flag = (cnt >= 8) ? 1 : 0;
}

// ---- normalize inputs to clean bf16 in ws ----
__global__ __launch_bounds__(256) void conv_in(
    const int* __restrict__ flag,
    const void* __restrict__ seq, const void* __restrict__ wq,
    const void* __restrict__ wk,  const void* __restrict__ wv,
    const void* __restrict__ bq,  const void* __restrict__ bk,
    const void* __restrict__ bv,  const void* __restrict__ pm,
    unsigned short* __restrict__ ws)
{
    const int f = *flag;
    unsigned int t = blockIdx.x * 256u + threadIdx.x;   // grid 28700 -> 7,347,200
    const void* src; unsigned int idx; unsigned short* dst;
    if (t < 4194304u)      { src = seq; idx = t;            dst = ws + 12582912u; }
    else if (t < 5242880u) { src = wq;  idx = t - 4194304u; dst = ws + 16777216u; }
    else if (t < 6291456u) { src = wk;  idx = t - 5242880u; dst = ws + 17825792u; }
    else if (t < 7340032u) { src = wv;  idx = t - 6291456u; dst = ws + 18874368u; }
    else if (t < 7341056u) { src = bq;  idx = t - 7340032u; dst = ws + 19922944u; }
    else if (t < 7342080u) { src = bk;  idx = t - 7341056u; dst = ws + 19923968u; }
    else if (t < 7343104u) { src = bv;  idx = t - 7342080u; dst = ws + 19924992u; }
    else                   { src = pm;  idx = t - 7343104u; dst = ws + 19927040u; }
    unsigned short v;
    if (f) v = f2bf(((const float*)src)[idx]);
    else   v = scrub1(((const unsigned short*)src)[idx]);
    dst[idx] = v;
}

// ---------------- QKV projection, m97 pattern (unpadded LDS + global_load_lds) --------
// grid (32,8,3) block 256. z==0/1 -> (B,H,L,DH); z==2 -> V^T per head: [bh][d][l].
__global__ __launch_bounds__(256) void qkv_proj(
    const unsigned short* __restrict__ X,
    const unsigned short* __restrict__ Wq, const unsigned short* __restrict__ bq,
    const unsigned short* __restrict__ Wk, const unsigned short* __restrict__ bk,
    const unsigned short* __restrict__ Wv, const unsigned short* __restrict__ bv,
    unsigned short* __restrict__ dst_base)
{
    const int z = blockIdx.z;
    const unsigned short* W    = (z == 0) ? Wq : ((z == 1) ? Wk : Wv);
    const unsigned short* bias = (z == 0) ? bq : ((z == 1) ? bk : bv);
    unsigned short* dst = dst_base + (size_t)z * (4096u * 1024u);

    __shared__ __align__(16) unsigned short As[128][64];  // unpadded (global_load_lds reqt)
    __shared__ __align__(16) unsigned short Bs[128][64];

    const int tid  = threadIdx.x;
    const int lane = tid & 63;
    const int wave = tid >> 6;
    const int quad = lane >> 4, r16 = lane & 15;
    const int wr = wave >> 1, wc = wave & 1;
    const int m0 = blockIdx.x * 128;
    const int n0 = blockIdx.y * 128;

    floatx4 acc[4][4];
#pragma unroll
    for (int i = 0; i < 4; ++i)
#pragma unroll
        for (int j = 0; j < 4; ++j)
#pragma unroll
            for (int r = 0; r < 4; ++r) acc[i][j][r] = 0.f;

    for (int k0 = 0; k0 < 1024; k0 += 64) {
        __syncthreads();
#if HAVE_GLL
#pragma unroll
        for (int c = 0; c < 4; ++c) {
            int seg = wave * 4 + c;                       // 0..15, 1KB LDS each
            int row = seg * 8 + (lane >> 3);
            int col = (lane & 7) * 8;
            gll16(X + (size_t)(m0 + row) * 1024 + k0 + col, &As[0][0] + seg * 512);
            gll16(W + (size_t)(n0 + row) * 1024 + k0 + col, &Bs[0][0] + seg * 512);
        }
#else
#pragma unroll
        for (int v = 0; v < 4; ++v) {
            int vi  = tid + v * 256;
            int row = vi >> 3, cv = (vi & 7) << 3;
            *(uint4*)&As[row][cv] = *(const uint4*)(X + (size_t)(m0 + row) * 1024 + k0 + cv);
            *(uint4*)&Bs[row][cv] = *(const uint4*)(W + (size_t)(n0 + row) * 1024 + k0 + cv);
        }
#endif
        __syncthreads();

#pragma unroll
        for (int kk = 0; kk < 2; ++kk) {
            short8 a[4], b[4];
#pragma unroll
            for (int i = 0; i < 4; ++i)
                a[i] = *(const short8*)&As[wr * 64 + i * 16 + r16][kk * 32 + quad * 8];
#pragma unroll
            for (int j = 0; j < 4; ++j)
                b[j] = *(const short8*)&Bs[wc * 64 + j * 16 + r16][kk * 32 + quad * 8];
#pragma unroll
            for (int i = 0; i < 4; ++i)
#pragma unroll
                for (int j = 0; j < 4; ++j)
                    acc[i][j] = __builtin_amdgcn_mfma_f32_16x16x32_bf16(a[i], b[j], acc[i][j], 0, 0, 0);
        }
    }

#pragma unroll
    for (int j = 0; j < 4; ++j) {
        int n = n0 + wc * 64 + j * 16 + r16;
        float bvf = bf2f(bias[n]);
        int h = n >> 6, d = n & 63;
#pragma unroll
        for (int i = 0; i < 4; ++i) {
            int m_base = m0 + wr * 64 + i * 16 + quad * 4;      // 4 consecutive rows
            int b = m_base >> 10, l0 = m_base & 1023;
            if (z == 2) {
                // V^T: [bh*64+d][l], 4 consecutive l -> one 8B store (full-line coverage/blk)
                ushort4 st;
                st.x = f2bf(acc[i][j][0] + bvf); st.y = f2bf(acc[i][j][1] + bvf);
                st.z = f2bf(acc[i][j][2] + bvf); st.w = f2bf(acc[i][j][3] + bvf);
                *(ushort4*)&dst[(((size_t)(b * 16 + h)) * 64 + d) * 1024 + l0] = st;
            } else {
#pragma unroll
                for (int r = 0; r < 4; ++r)
                    dst[(((size_t)(b * 16 + h)) * 1024 + (l0 + r)) * 64 + d] = f2bf(acc[i][j][r] + bvf);
            }
        }
    }
}

// ---------------- Flash attention: Q-tile 128, K-tile 128, V^T input ----------------
// grid 512 linear; complementary qi pairing so bid and bid+256 get qi and 7-qi
// (per-CU work uniform at ~9 k-iters). 4 waves x 2 fragments of 16 q-rows.
__global__ __launch_bounds__(256) void attn(
    const unsigned short* __restrict__ Qw,     // (B,H,L,DH)
    const unsigned short* __restrict__ Kw,     // (B,H,L,DH)
    const unsigned short* __restrict__ Vt_g,   // (B*H, DH, L)  transposed
    const unsigned short* __restrict__ pmask,  // (B, L) clean bf16
    const int* __restrict__ flag,
    void* __restrict__ out)                    // (B,L,D) bf16 or fp32 per flag
{
    __shared__ __align__(16) unsigned short Ks[128][64];   // [key][dh]   unpadded (gll)
    __shared__ __align__(16) unsigned short Vs[64][128];   // [dh][key]   unpadded (gll)
    __shared__ __align__(16) unsigned short Ps[4][16][136];

    const int tid  = threadIdx.x;
    const int lane = tid & 63;
    const int wave = tid >> 6;
    const int quad = lane >> 4, r16 = lane & 15;

    const int bid  = blockIdx.x;
    const int half = bid >> 8, rr = bid & 255;
    const int bh   = half * 32 + (rr >> 3);
    const int qi   = half ? (7 - (rr & 7)) : (rr & 7);
    const int b    = bh >> 4, h = bh & 15;
    const int q0   = qi * 128;
    const int fout = *flag;

    const size_t base = (size_t)bh * (1024 * 64);
    const unsigned short* Qg = Qw + base;
    const unsigned short* Kg = Kw + base;
    const unsigned short* Vg = Vt_g + base;   // row stride 1024 (l), 64 rows (d)

    // two Q fragments per wave: rows q0 + f*64 + wave*16 + r16
    short8 aq[2][2];
#pragma unroll
    for (int f = 0; f < 2; ++f) {
        int qrow = q0 + f * 64 + wave * 16 + r16;
        aq[f][0] = *(const short8*)(Qg + (size_t)qrow * 64 + quad * 8);
        aq[f][1] = *(const short8*)(Qg + (size_t)qrow * 64 + 32 + quad * 8);
    }

    float m_st[2][4], l_st[2][4];
    floatx4 o[2][4];
#pragma unroll
    for (int f = 0; f < 2; ++f)
#pragma unroll
        for (int r = 0; r < 4; ++r) { m_st[f][r] = -1.0e30f; l_st[f][r] = 0.f; }
#pragma unroll
    for (int f = 0; f < 2; ++f)
#pragma unroll
        for (int j = 0; j < 4; ++j)
#pragma unroll
            for (int r = 0; r < 4; ++r) o[f][j][r] = 0.f;

    for (int kt = 0; kt <= qi; ++kt) {
        __syncthreads();   // prior iteration's Ks/Vs readers done
#if HAVE_GLL
#pragma unroll
        for (int c = 0; c < 4; ++c) {
            int seg = wave * 4 + c;
            {   // Ks: row len 64
                int row = seg * 8 + (lane >> 3);
                int col = (lane & 7) * 8;
                gll16(Kg + (size_t)(kt * 128 + row) * 64 + col, &Ks[0][0] + seg * 512);
            }
            {   // Vs: row len 128 (keys), from V^T global rows (d)
                int row = seg * 4 + (lane >> 4);
                int col = (lane & 15) * 8;
                gll16(Vg + (size_t)row * 1024 + kt * 128 + col, &Vs[0][0] + seg * 512);
            }
        }
#else
#pragma unroll
        for (int v = 0; v < 4; ++v) {
            int vi  = tid + v * 256;
            {
                int row = vi >> 3, cv = (vi & 7) << 3;
                *(uint4*)&Ks[row][cv] = *(const uint4*)(Kg + (size_t)(kt * 128 + row) * 64 + cv);
            }
            {
                int row = vi >> 4, cv = (vi & 15) << 3;
                *(uint4*)&Vs[row][cv] = *(const uint4*)(Vg + (size_t)row * 1024 + kt * 128 + cv);
            }
        }
#endif
        __syncthreads();   // staging visible (compiler drains vmcnt(0) before barrier)

        // padding mask for this key tile (shared by both fragments)
        const int key_base = kt * 128;
        float pm8[8];
#pragma unroll
        for (int j = 0; j < 8; ++j)
            pm8[j] = bf2f(pmask[b * LL + key_base + j * 16 + r16]);

#pragma unroll
        for (int f = 0; f < 2; ++f) {
            const int my_q = q0 + f * 64 + wave * 16 + quad * 4;

            floatx4 s[8];
#pragma unroll
            for (int j = 0; j < 8; ++j)
#pragma unroll
                for (int r = 0; r < 4; ++r) s[j][r] = 0.f;
#pragma unroll
            for (int j = 0; j < 8; ++j) {
                short8 bk0 = *(const short8*)&Ks[j * 16 + r16][quad * 8];
                s[j] = __builtin_amdgcn_mfma_f32_16x16x32_bf16(aq[f][0], bk0, s[j], 0, 0, 0);
                short8 bk1 = *(const short8*)&Ks[j * 16 + r16][32 + quad * 8];
                s[j] = __builtin_amdgcn_mfma_f32_16x16x32_bf16(aq[f][1], bk1, s[j], 0, 0, 0);
            }

#pragma unroll
            for (int j = 0; j < 8; ++j) {
                int key = key_base + j * 16 + r16;
#pragma unroll
                for (int r = 0; r < 4; ++r) {
                    float sc = s[j][r] * 0.125f + pm8[j];
                    if (key > my_q + r) sc -= 1.0e9f;
                    s[j][r] = sc;
                }
            }

#pragma unroll
            for (int r = 0; r < 4; ++r) {
                float mx = s[0][r];
#pragma unroll
                for (int j = 1; j < 8; ++j) mx = fmaxf(mx, s[j][r]);
                mx = fmaxf(mx, __shfl_xor(mx, 1));
                mx = fmaxf(mx, __shfl_xor(mx, 2));
                mx = fmaxf(mx, __shfl_xor(mx, 4));
                mx = fmaxf(mx, __shfl_xor(mx, 8));
                float m_new = fmaxf(m_st[f][r], mx);
                float alpha = __expf(m_st[f][r] - m_new);
                float rs = 0.f;
#pragma unroll
                for (int j = 0; j < 8; ++j) {
                    float p = __expf(s[j][r] - m_new);
                    s[j][r] = p;
                    rs += p;
                }
                rs += __shfl_xor(rs, 1);
                rs += __shfl_xor(rs, 2);
                rs += __shfl_xor(rs, 4);
                rs += __shfl_xor(rs, 8);
                l_st[f][r] = l_st[f][r] * alpha + rs;
                m_st[f][r] = m_new;
#pragma unroll
                for (int j2 = 0; j2 < 4; ++j2) o[f][j2][r] *= alpha;
            }

            // WAR fence: prior PV reads of Ps[wave] must retire before overwrite.
            // Per-wave lgkmcnt handshake (exonerated by R1: barrier variant failed same).
            asm volatile("s_waitcnt lgkmcnt(0)" ::: "memory");
#pragma unroll
            for (int j = 0; j < 8; ++j)
#pragma unroll
                for (int r = 0; r < 4; ++r)
                    Ps[wave][quad * 4 + r][j * 16 + r16] = f2bf(s[j][r]);
            // RAW fence: DS ops complete in-order per wave once lgkmcnt drains
            asm volatile("s_waitcnt lgkmcnt(0)" ::: "memory");

#pragma unroll
            for (int kk4 = 0; kk4 < 4; ++kk4) {
                short8 ap = *(const short8*)&Ps[wave][r16][kk4 * 32 + quad * 8];
#pragma unroll
                for (int j2 = 0; j2 < 4; ++j2) {
                    short8 bv = *(const short8*)&Vs[j2 * 16 + r16][kk4 * 32 + quad * 8];
                    o[f][j2] = __builtin_amdgcn_mfma_f32_16x16x32_bf16(ap, bv, o[f][j2], 0, 0, 0);
                }
            }
        }
    }

    // epilogue: direct store to d_out in flagged dtype
#pragma unroll
    for (int f = 0; f < 2; ++f) {
        const int my_q = q0 + f * 64 + wave * 16 + quad * 4;
#pragma unroll
        for (int j2 = 0; j2 < 4; ++j2) {
            int d = j2 * 16 + r16;
#pragma unroll
            for (int r = 0; r < 4; ++r) {
                int qrow = my_q + r;
                float val = o[f][j2][r] / fmaxf(l_st[f][r], 1.0e-30f);
                size_t oidx = ((size_t)(b * 1024 + qrow)) * 1024 + h * 64 + d;
                if (fout) ((float*)out)[oidx] = val;
                else      ((unsigned short*)out)[oidx] = f2bf(val);
            }
        }
    }
}

__global__ __launch_bounds__(256) void fill_sentinel(unsigned short* __restrict__ out,
                                                     unsigned short v, unsigned int n)
{
    unsigned int t = blockIdx.x * 256u + threadIdx.x;
    if (t < n) out[t] = v;
}

extern "C" void kernel_launch(void* const* d_in, const int* in_sizes, int n_in,
                              void* d_out, int out_size, void* d_ws, size_t ws_size,
                              hipStream_t stream) {
    bool sizes_ok = (n_in == 9) && in_sizes[0] == 4194304 && in_sizes[1] == 4096 &&
                    in_sizes[2] == 1048576 && in_sizes[3] == 1048576 && in_sizes[4] == 1024 &&
                    in_sizes[5] == 1048576 && in_sizes[6] == 1024 && in_sizes[7] == 1048576 &&
                    in_sizes[8] == 1024 && out_size == 4194304;
    if (!sizes_ok) {
        fill_sentinel<<<16384, 256, 0, stream>>>((unsigned short*)d_out, 0x42C8 /*100*/, 4194304u);
        return;
    }
    if (ws_size < 50331652u) {
        fill_sentinel<<<16384, 256, 0, stream>>>((unsigned short*)d_out, 0x4348 /*200*/, 4194304u);
        return;
    }

    unsigned short* ws = (unsigned short*)d_ws;
    int* flag = (int*)((char*)d_ws + 50331648u);

    probe_dtype<<<1, 256, 0, stream>>>((const unsigned short*)d_in[0], flag);

    conv_in<<<28700, 256, 0, stream>>>(flag,
        d_in[0], d_in[3], d_in[5], d_in[7], d_in[4], d_in[6], d_in[8], d_in[1], ws);

    const unsigned short* cseq = ws + 12582912u;
    const unsigned short* cwq  = ws + 16777216u;
    const unsigned short* cwk  = ws + 17825792u;
    const unsigned short* cwv  = ws + 18874368u;
    const unsigned short* cbq  = ws + 19922944u;
    const unsigned short* cbk  = ws + 19923968u;
    const unsigned short* cbv  = ws + 19924992u;
    const unsigned short* cpm  = ws + 19927040u;

    dim3 g1(32, 8, 3);
    qkv_proj<<<g1, 256, 0, stream>>>(cseq, cwq, cbq, cwk, cbk, cwv, cbv, ws);

    attn<<<512, 256, 0, stream>>>(ws, ws + 4194304u, ws + 8388608u, cpm, flag, d_out);
}